// Round 13
// baseline (2124.141 us; speedup 1.0000x reference)
//
#include <hip/hip_runtime.h>
#include <hip/hip_bf16.h>
#include <cstdint>
#include <cstddef>

#define NN 100000
#define NE 800000
#define NG 64
#define NT 4
#define DD 150
#define HS 160    // padded h/inc row stride (floats): 640 B = 10 cache lines, 16B aligned
#define HIDN 512
#define NPASS 5
#define NBINS (NN*NT)
#define RPB 16     // readout partial blocks per graph

typedef short  s8v  __attribute__((ext_vector_type(8)));   // 8 bf16 (4 VGPRs)
typedef float  f32x4 __attribute__((ext_vector_type(4)));

static __device__ __forceinline__ float sigmoidf_(float x){ return 1.f/(1.f+expf(-x)); }
static __device__ __forceinline__ short f2bf(float x){
  __hip_bfloat16 b = __float2bfloat16(x);
  return *(short*)&b;
}
static __device__ __forceinline__ float bf2f(short s){
  union { unsigned u; float f; } v; v.u = ((unsigned)(unsigned short)s) << 16; return v.f;
}
// split fp32 into hi bf16 + residual bf16 (Markidis): x ~= hi + lo
static __device__ __forceinline__ void split_bf(float x, short& hi, short& lo){
  hi = f2bf(x);
  lo = f2bf(x - bf2f(hi));
}

// stage one 20 KB B-slice (1280 x 16B chunks) direct to LDS via global_load_lds:
// no VGPR round-trip, no ds_write. LDS dest = wave-uniform base + lane*16 (HW rule);
// global src is per-lane. All threads execute (no divergence).
static __device__ __forceinline__ void stage16(const unsigned short* __restrict__ g,
                                               short* l, int tid){
  const int wave = tid >> 6, lane = tid & 63;
  #pragma unroll
  for (int k2 = 0; k2 < 5; k2++){
    const int cb = k2*256 + wave*64;                 // wave-uniform chunk base
    const unsigned short* gp = g + (size_t)(cb + lane)*8;
    short* lp = l + (size_t)cb*8;                    // wave-uniform LDS base
    __builtin_amdgcn_global_load_lds(
        (const __attribute__((address_space(1))) void*)gp,
        (__attribute__((address_space(3))) void*)lp, 16, 0, 0);
  }
}

// ---------------- setup: counting sort of edges by (dst,type) ----------------

__global__ void count_kernel(const int* __restrict__ dst, const int* __restrict__ typ,
                             unsigned* __restrict__ deg){
  int e = blockIdx.x*256 + threadIdx.x;
  if (e < NE) atomicAdd(&deg[dst[e]*NT + typ[e]], 1u);
}

__device__ unsigned block_excl_base(unsigned threadSum){
  const int tid = threadIdx.x;
  const int lane = tid & 63, wid = tid >> 6;
  unsigned s = threadSum;
  #pragma unroll
  for (int d = 1; d < 64; d <<= 1){ unsigned t = __shfl_up(s, d); if (lane >= d) s += t; }
  __shared__ unsigned wsum[4];
  if (lane == 63) wsum[wid] = s;
  __syncthreads();
  unsigned base = 0;
  for (int w = 0; w < wid; w++) base += wsum[w];
  return base + s - threadSum;
}

__global__ void scan_reduce(const unsigned* __restrict__ deg, unsigned* __restrict__ bsum){
  const int base = blockIdx.x*1024 + threadIdx.x*4;
  unsigned s = 0;
  #pragma unroll
  for (int i = 0; i < 4; i++){ const int idx = base+i; if (idx < NBINS) s += deg[idx]; }
  #pragma unroll
  for (int d = 1; d < 64; d <<= 1) s += __shfl_down(s, d);
  __shared__ unsigned ws4[4];
  const int lane = threadIdx.x & 63, wid = threadIdx.x >> 6;
  if (lane == 0) ws4[wid] = s;
  __syncthreads();
  if (threadIdx.x == 0) bsum[blockIdx.x] = ws4[0]+ws4[1]+ws4[2]+ws4[3];
}

__global__ void scan_block(unsigned* bsum, int n){
  const int tid = threadIdx.x;
  unsigned v[4]; unsigned s = 0;
  #pragma unroll
  for (int i = 0; i < 4; i++){ const int idx = tid*4+i; v[i] = (idx < n) ? bsum[idx] : 0u; s += v[i]; }
  unsigned run = block_excl_base(s);
  #pragma unroll
  for (int i = 0; i < 4; i++){ const int idx = tid*4+i; if (idx < n) bsum[idx] = run; run += v[i]; }
}

__global__ void scan_final(const unsigned* __restrict__ deg, const unsigned* __restrict__ bsum,
                           unsigned* __restrict__ off){
  const int tid = threadIdx.x;
  const int base0 = blockIdx.x*1024 + tid*4;
  unsigned v[4]; unsigned s = 0;
  #pragma unroll
  for (int i = 0; i < 4; i++){ const int idx = base0+i; v[i] = (idx < NBINS) ? deg[idx] : 0u; s += v[i]; }
  unsigned run = block_excl_base(s) + bsum[blockIdx.x];
  #pragma unroll
  for (int i = 0; i < 4; i++){ const int idx = base0+i; if (idx < NBINS) off[idx] = run; run += v[i]; }
  if (blockIdx.x == 0 && tid == 0) off[NBINS] = NE;
}

__global__ void scatter_sort(const int* __restrict__ src, const int* __restrict__ dst,
                             const int* __restrict__ typ, unsigned* __restrict__ cur,
                             int* __restrict__ srcSorted){
  int e = blockIdx.x*256 + threadIdx.x;
  if (e < NE){
    const int bin = dst[e]*NT + typ[e];
    const unsigned p = atomicAdd(&cur[bin], 1u);
    srcSorted[p] = src[e];
  }
}

// ---------------- h init: copy nodes into padded-stride buffer, zero pads ----------
__global__ void init_h(const float* __restrict__ nodes, float* __restrict__ h0){
  const long long idx = (long long)blockIdx.x*256 + threadIdx.x;
  if (idx >= (long long)NN*HS) return;
  const int row = (int)(idx / HS), col = (int)(idx % HS);
  float v = 0.f;
  if (col < DD) v = nodes[(size_t)row*DD + col];
  h0[idx] = v;
}

// ---- pack W_e -> slice-ordered msg B-frags: BfE2[(t*5+s)][i*2+c][512], c:0=hi 1=lo
__global__ void build_bfrag_msg(const float* __restrict__ W, unsigned short* __restrict__ out){
  const int idx = blockIdx.x*256 + threadIdx.x;
  if (idx >= NT*5*10*2*512) return;
  const int w = idx & 511;
  int r = idx >> 9;
  const int c = r % 2;  r /= 2;
  const int i = r % 10; r /= 10;
  const int s = r % 5;  const int t = r / 5;
  const int l = w >> 3, j = w & 7;
  const int n  = 16*i + (l & 15);
  const int kk = 32*s + (l >> 4)*8 + j;
  float v = 0.f;
  if (n < DD && kk < DD) v = W[(size_t)(t*DD + n)*DD + kk];
  short hi, lo; split_bf(v, hi, lo);
  out[(size_t)((t*5 + s)*20 + i*2 + c)*512 + w] = (unsigned short)(c ? lo : hi);
}

// ---- pack w_ih/w_hh -> slice-ordered gru B-frags (20 KB slices, 2 products each):
// BfG[(iT*3+part)][u*10 + c*5 + s][512]; product P=part*2+u: g=P>>1, src=P&1 (0=I,1=H)
__global__ void build_bfrag_gru(const float* __restrict__ w_ih, const float* __restrict__ w_hh,
                                unsigned short* __restrict__ out){
  const int idx = blockIdx.x*256 + threadIdx.x;
  if (idx >= 10*3*2*2*5*512) return;
  const int w = idx & 511;
  int r = idx >> 9;
  const int s = r % 5;    r /= 5;
  const int c = r % 2;    r /= 2;
  const int u = r % 2;    r /= 2;
  const int part = r % 3; const int iT = r / 3;
  const int P = part*2 + u;
  const int g = P >> 1;
  const float* W = (P & 1) ? w_hh : w_ih;
  const int l = w >> 3, j = w & 7;
  const int n  = 16*iT + (l & 15);
  const int kk = 32*s + (l >> 4)*8 + j;
  float v = 0.f;
  if (n < DD && kk < DD) v = W[(size_t)(g*DD + n)*DD + kk];
  short hi, lo; split_bf(v, hi, lo);
  out[(size_t)((iT*3 + part)*20 + u*10 + c*5 + s)*512 + w] = (unsigned short)(c ? lo : hi);
}

// 3-product split-precision accumulate: acc += (Ahi+Alo)*(Bhi+Blo) minus lo*lo
#define MFMA3(acc, ahi, alo, bhi, blo) \
  acc = __builtin_amdgcn_mfma_f32_16x16x32_bf16(ahi, bhi, acc, 0,0,0); \
  acc = __builtin_amdgcn_mfma_f32_16x16x32_bf16(alo, bhi, acc, 0,0,0); \
  acc = __builtin_amdgcn_mfma_f32_16x16x32_bf16(ahi, blo, acc, 0,0,0);

// ---------------- kernel A: gather + message GEMM -> inc (global) -------------
// 256 thr / 4 waves / 64 rows; LDS 2x20 KB -> 4 blocks/CU (4 x 40960 = 160 KiB).
// B-slices staged direct-to-LDS via global_load_lds (width 16). One barrier per
// slice except the last (dead). CSR offsets for all 4 types loaded as one uint4
// + scalar (removes 4 serial ~300-cyc index chains per wave).
__global__ __launch_bounds__(256, 2) void msg_kernel(
    const float* __restrict__ h, const int* __restrict__ srcS,
    const unsigned* __restrict__ off, const unsigned* __restrict__ deg,
    const float* __restrict__ b_e,
    const unsigned short* __restrict__ BfE2,
    float* __restrict__ inc)
{
  __shared__ short Bs[2][20*512];   // 2 x 20480 B
  const int tid = threadIdx.x, wave = tid >> 6, l = tid & 63;
  const int m = l & 15, q = l >> 4, q8 = q*8;
  const int arow = blockIdx.x*64 + wave*16 + m;
  const bool av = (arow < NN);
  const int lb8 = l*8;

  f32x4 acc[10];
  #pragma unroll
  for (int i = 0; i < 10; i++) acc[i] = (f32x4)(0.0f);

  // all 5 CSR offsets for this row in one uint4 + scalar
  unsigned ob0=0, ob1=0, ob2=0, ob3=0, ob4=0;
  if (av){
    const uint4 ob = *(const uint4*)&off[arow*NT];
    ob0=ob.x; ob1=ob.y; ob2=ob.z; ob3=ob.w;
    ob4 = off[arow*NT + 4];
  }

  // prologue: slices 0 and 1 direct to LDS (land during first gather)
  stage16(BfE2,          &Bs[0][0], tid);
  stage16(BfE2 + 10240,  &Bs[1][0], tid);
  __syncthreads();

  for (int t = 0; t < NT; t++){
    // pre-gather: stage slice t*5+1 for t>0 (t=0's slice 1 staged in prologue).
    if (t > 0) stage16(BfE2 + (size_t)(t*5 + 1)*10240, &Bs[(t*5+1) & 1][0], tid);

    // ---- gather type-t neighbor rows ----
    float a[5][8];
    #pragma unroll
    for (int s = 0; s < 5; s++)
      #pragma unroll
      for (int j = 0; j < 8; j++) a[s][j] = 0.f;

    const int lo = (int)((t==0)?ob0:(t==1)?ob1:(t==2)?ob2:ob3);
    const int hi = (int)((t==0)?ob1:(t==1)?ob2:(t==2)?ob3:ob4);
    int e = lo;
    int i0 = (e   < hi) ? srcS[e]   : 0;
    int i1 = (e+1 < hi) ? srcS[e+1] : -1;
    while (e < hi){
      const int n0 = (e+2 < hi) ? srcS[e+2] : 0;
      const int n1 = (e+3 < hi) ? srcS[e+3] : -1;
      const float* p0 = h + (size_t)i0*HS + q8;
      const float* p1 = h + (size_t)(i1 < 0 ? 0 : i1)*HS + q8;
      const float w1 = (i1 < 0) ? 0.f : 1.f;
      f32x4 v[10], u[10];
      #pragma unroll
      for (int s = 0; s < 5; s++){
        v[2*s]   = *(const f32x4*)(p0 + 32*s);
        v[2*s+1] = *(const f32x4*)(p0 + 32*s + 4);
      }
      #pragma unroll
      for (int s = 0; s < 5; s++){
        u[2*s]   = *(const f32x4*)(p1 + 32*s);
        u[2*s+1] = *(const f32x4*)(p1 + 32*s + 4);
      }
      #pragma unroll
      for (int s = 0; s < 5; s++){
        #pragma unroll
        for (int j = 0; j < 4; j++){
          a[s][j]   += v[2*s][j];
          a[s][j]   = fmaf(w1, u[2*s][j], a[s][j]);
          a[s][4+j] += v[2*s+1][j];
          a[s][4+j] = fmaf(w1, u[2*s+1][j], a[s][4+j]);
        }
      }
      e += 2; i0 = n0; i1 = n1;
    }

    s8v af_hi[5], af_lo[5];
    #pragma unroll
    for (int s = 0; s < 5; s++)
      #pragma unroll
      for (int j = 0; j < 8; j++){
        short h2, l2; split_bf(a[s][j], h2, l2);
        af_hi[s][j] = h2; af_lo[s][j] = l2;
      }

    // ---- 5 staged MFMA slices for this t; stage slice sidx+1 at slice top ----
    #pragma unroll
    for (int st = 0; st < 5; st++){
      const int sidx = t*5 + st;
      if (st >= 1 && sidx + 1 < 20)
        stage16(BfE2 + (size_t)(sidx+1)*10240, &Bs[(sidx+1) & 1][0], tid);
      const short* bsr = &Bs[sidx & 1][0];
      #pragma unroll
      for (int i = 0; i < 10; i++){
        const s8v bh = *(const s8v*)(bsr + (i*2+0)*512 + lb8);
        const s8v bl = *(const s8v*)(bsr + (i*2+1)*512 + lb8);
        MFMA3(acc[i], af_hi[st], af_lo[st], bh, bl)
      }
      if (sidx < 19) __syncthreads();   // drains staged loads + frees buf[sidx&1]
    }
  }

  // store inc (+ deg@b_e bias) in C-layout; cols >= DD zeroed (MFMA K pad later)
  const int crow0 = blockIdx.x*64 + wave*16 + q*4;
  #pragma unroll
  for (int r = 0; r < 4; r++){
    const int crow = crow0 + r;
    if (crow < NN){
      const uint4 dg = *(const uint4*)(&deg[crow*NT]);
      const float d0=(float)dg.x, d1=(float)dg.y, d2=(float)dg.z, d3=(float)dg.w;
      float* op = inc + (size_t)crow*HS;
      #pragma unroll
      for (int i = 0; i < 10; i++){
        const int c = 16*i + m;
        float val = 0.f;
        if (c < DD)
          val = acc[i][r] + fmaf(d0, b_e[c], fmaf(d1, b_e[DD+c],
                  fmaf(d2, b_e[2*DD+c], d3*b_e[3*DD+c])));
        op[c] = val;
      }
    }
  }
}

// ---------------- kernel B: gi/gh GEMMs + GRU, IN PLACE over inc --------------
// 256 thr / 4 waves / 64 rows; 30 x 20 KB slices double-buffered via
// global_load_lds. Deferred hnext stores in hn[10][4] REGISTERS: the (iT,part)
// loops are FULLY UNROLLED so every hn index is compile-time-constant
// (round-12 bug: runtime iT=k/3 put hn in scratch -> +90 MB HBM traffic,
// VGPR_Count 80 + localMem; guide rule #20). No stores between barriers.
// In-place safe: block reads only its own 64 inc rows, overwrites same rows.
__global__ __launch_bounds__(256, 2) void gru_kernel(
    const float* __restrict__ h, float* __restrict__ incnext,
    const unsigned short* __restrict__ BfG,
    const float* __restrict__ b_ih, const float* __restrict__ b_hh)
{
  __shared__ short Bs[2][20*512];   // 2 x 20480 B
  const int tid = threadIdx.x, wave = tid >> 6, l = tid & 63;
  const int m = l & 15, q = l >> 4, q8 = q*8;
  const int arow = blockIdx.x*64 + wave*16 + m;
  const bool av = (arow < NN);
  const int lb8 = l*8;
  const int crow0 = blockIdx.x*64 + wave*16 + q*4;

  // stage slice 0 first so it lands under the A-fragment build
  stage16(BfG, &Bs[0][0], tid);

  // A-fragments: inc and hcur from global padded rows (uniform aligned loads)
  s8v afi_h[5], afi_l[5], afh_h[5], afh_l[5];
  {
    const float* ip = incnext + (size_t)(av ? arow : 0)*HS;
    const float* hp = h       + (size_t)(av ? arow : 0)*HS;
    #pragma unroll
    for (int s = 0; s < 5; s++){
      const int b = 32*s + q8;
      const f32x4 x0 = *(const f32x4*)(ip + b), x1 = *(const f32x4*)(ip + b + 4);
      const f32x4 y0 = *(const f32x4*)(hp + b), y1 = *(const f32x4*)(hp + b + 4);
      #pragma unroll
      for (int j = 0; j < 4; j++){
        short h2, l2;
        split_bf(x0[j], h2, l2); afi_h[s][j]   = h2; afi_l[s][j]   = l2;
        split_bf(x1[j], h2, l2); afi_h[s][4+j] = h2; afi_l[s][4+j] = l2;
        split_bf(y0[j], h2, l2); afh_h[s][j]   = h2; afh_l[s][j]   = l2;
        split_bf(y1[j], h2, l2); afh_h[s][4+j] = h2; afh_l[s][4+j] = l2;
      }
    }
  }
  __syncthreads();   // slice 0 landed

  f32x4 aR=(f32x4)(0.f), aZ=(f32x4)(0.f);
  float hv[4] = {0.f,0.f,0.f,0.f};
  float hn[10][4];   // deferred hnext values; statically indexed (full unroll)

  #pragma unroll
  for (int iT = 0; iT < 10; iT++){
    const int d = 16*iT + m;
    #pragma unroll
    for (int part = 0; part < 3; part++){
      const int k = iT*3 + part;
      // stage slice k+1 direct to LDS
      if (k + 1 < 30) stage16(BfG + (size_t)(k+1)*10240, &Bs[(k+1) & 1][0], tid);

      if (part == 0){
        #pragma unroll
        for (int r = 0; r < 4; r++){
          hv[r] = 0.f;
          if (crow0 + r < NN && d < DD) hv[r] = h[(size_t)(crow0+r)*HS + d];
        }
      }

      // slice k: u=0 frags pair with afi, u=1 with afh; independent tI/tH chains
      const short* bsr = &Bs[k & 1][0];
      f32x4 tI = (f32x4)(0.f), tH = (f32x4)(0.f);
      #pragma unroll
      for (int s = 0; s < 5; s++){
        const s8v b0h = *(const s8v*)(bsr + (     s)*512 + lb8);
        const s8v b0l = *(const s8v*)(bsr + ( 5 + s)*512 + lb8);
        const s8v b1h = *(const s8v*)(bsr + (10 + s)*512 + lb8);
        const s8v b1l = *(const s8v*)(bsr + (15 + s)*512 + lb8);
        MFMA3(tI, afi_h[s], afi_l[s], b0h, b0l)
        MFMA3(tH, afh_h[s], afh_l[s], b1h, b1l)
      }

      if (part == 0){
        aR = tI + tH;
      } else if (part == 1){
        aZ = tI + tH;
      } else {            // part 2: tI = N_i product, tH = N_h product
        const float br   = (d < DD) ? (b_ih[d]    + b_hh[d])    : 0.f;
        const float bz   = (d < DD) ? (b_ih[DD+d] + b_hh[DD+d]) : 0.f;
        const float bin2 = (d < DD) ? b_ih[2*DD+d] : 0.f;
        const float bhn  = (d < DD) ? b_hh[2*DD+d] : 0.f;
        #pragma unroll
        for (int r = 0; r < 4; r++){
          const float rr = sigmoidf_(aR[r] + br);
          const float zz = sigmoidf_(aZ[r] + bz);
          const float nn = tanhf(tI[r] + bin2 + rr*(tH[r] + bhn));
          hn[iT][r] = (1.f - zz)*nn + zz*hv[r];
        }
      }
      if (k < 29) __syncthreads();   // drains staged loads + frees buf[k&1]
    }
  }

  // deferred hnext stores (cols 150..159 keep msg's zeros; d<DD guard)
  #pragma unroll
  for (int iT = 0; iT < 10; iT++){
    const int d = 16*iT + m;
    if (d < DD){
      #pragma unroll
      for (int r = 0; r < 4; r++){
        const int crow = crow0 + r;
        if (crow < NN) incnext[(size_t)crow*HS + d] = hn[iT][r];
      }
    }
  }
}

// ---------------- readout: two-stage segment sum, log/nan/relu, concat ----------------
__global__ void readout1(const float* __restrict__ h, const int* __restrict__ gids,
                         float* __restrict__ part){
  const int g = blockIdx.x >> 4, s = blockIdx.x & (RPB-1);
  const int tid = threadIdx.x;
  __shared__ int sb[2];
  if (tid < 2){
    const int target = g + tid;
    int lo = 0, hi = NN;
    while (lo < hi){ const int mid = (lo+hi) >> 1; if (gids[mid] < target) lo = mid+1; else hi = mid; }
    sb[tid] = lo;
  }
  __syncthreads();
  const int lo = sb[0], hi = sb[1];
  const int len = hi - lo;
  const int per = (len + RPB - 1) / RPB;
  const int nlo = lo + s*per;
  const int nhi = (nlo + per < hi) ? (nlo + per) : hi;
  if (tid < DD){
    float acc = 0.f;
    for (int n = nlo; n < nhi; n++) acc += h[(size_t)n*HS + tid];
    part[(size_t)blockIdx.x*DD + tid] = acc;
  }
}

__global__ void readout2(const float* __restrict__ part, const float* __restrict__ pclass,
                         float* __restrict__ xbuf){
  const int g = blockIdx.x, tid = threadIdx.x;
  if (tid < DD){
    float acc = 0.f;
    #pragma unroll
    for (int s = 0; s < RPB; s++) acc += part[(size_t)(g*RPB + s)*DD + tid];
    float l = logf(acc);            // log(neg)=NaN, log(0)=-inf
    if (isnan(l)) l = 0.f;          // nan -> 0
    l = fmaxf(l, 0.f);              // relu (also kills -inf)
    xbuf[g*(DD+1)+tid] = l;
  }
  if (tid == DD) xbuf[g*(DD+1)+DD] = pclass[g];
}

__global__ void fc1_kernel(const float* __restrict__ xbuf, const float* __restrict__ w,
                           const float* __restrict__ b, float* __restrict__ hid){
  const int g = blockIdx.x, tid = threadIdx.x;   // 512 threads
  __shared__ float xs[DD+1];
  if (tid < DD+1) xs[tid] = xbuf[g*(DD+1)+tid];
  __syncthreads();
  float acc = b[tid];
  for (int k = 0; k < DD+1; k++) acc = fmaf(xs[k], w[k*HIDN + tid], acc);
  hid[g*HIDN + tid] = (acc > 0.f) ? acc : 0.01f*acc;   // leaky_relu(0.01)
}

__global__ void fc2_kernel(const float* __restrict__ hid, const float* __restrict__ w,
                           const float* __restrict__ b, float* __restrict__ out){
  const int g = blockIdx.x, tid = threadIdx.x;   // 64 threads
  __shared__ float hs[HIDN];
  for (int i = tid; i < HIDN; i += 64) hs[i] = hid[g*HIDN + i];
  __syncthreads();
  if (tid < 10){
    float acc = b[tid];
    for (int k = 0; k < HIDN; k++) acc = fmaf(hs[k], w[k*10 + tid], acc);
    out[g*10 + tid] = acc;
  }
}

// ---------------- host orchestration ----------------
extern "C" void kernel_launch(void* const* d_in, const int* in_sizes, int n_in,
                              void* d_out, int out_size, void* d_ws, size_t ws_size,
                              hipStream_t stream)
{
  (void)in_sizes; (void)n_in; (void)out_size; (void)ws_size;
  const float* nodes  = (const float*)d_in[0];
  const float* pclass = (const float*)d_in[1];
  const int*   esrc   = (const int*)d_in[2];
  const int*   edst   = (const int*)d_in[3];
  const int*   etyp   = (const int*)d_in[4];
  const int*   gids   = (const int*)d_in[5];
  const float* W_e    = (const float*)d_in[6];
  const float* b_e    = (const float*)d_in[7];
  const float* w_ih   = (const float*)d_in[8];
  const float* w_hh   = (const float*)d_in[9];
  const float* b_ih   = (const float*)d_in[10];
  const float* b_hh   = (const float*)d_in[11];
  const float* fc1w   = (const float*)d_in[12];
  const float* fc1b   = (const float*)d_in[13];
  const float* fc2w   = (const float*)d_in[14];
  const float* fc2b   = (const float*)d_in[15];
  float* out = (float*)d_out;

  char* p = (char*)d_ws;
  auto alloc = [&](size_t bytes)->char* {
    char* r = p; p += ((bytes + 255) & ~(size_t)255); return r;
  };
  float*    h0   = (float*)alloc((size_t)NN*HS*4);          // 64 MB (ping)
  float*    h1   = (float*)alloc((size_t)NN*HS*4);          // 64 MB (pong; also inc)
  unsigned* deg  = (unsigned*)alloc((size_t)NBINS*4);
  unsigned* off  = (unsigned*)alloc((size_t)(NBINS+1)*4);
  unsigned* cur  = (unsigned*)alloc((size_t)NBINS*4);
  unsigned* bsum = (unsigned*)alloc(4096);
  int*      srcS = (int*)alloc((size_t)NE*4);
  unsigned short* BfE2 = (unsigned short*)alloc((size_t)20*20*512*2);   // 409,600 B
  unsigned short* BfG  = (unsigned short*)alloc((size_t)30*20*512*2);   // 614,400 B
  float*    part = (float*)alloc((size_t)NG*RPB*DD*4);
  float*    xbuf = (float*)alloc((size_t)NG*(DD+1)*4);
  float*    hidb = (float*)alloc((size_t)NG*HIDN*4);

  // --- per-launch setup: edge CSR sort + slice-packed weights + h init ---
  hipMemsetAsync(deg, 0, (size_t)NBINS*4, stream);
  count_kernel<<<(NE+255)/256, 256, 0, stream>>>(edst, etyp, deg);
  const int SCB = (NBINS + 1023)/1024;   // 391
  scan_reduce<<<SCB, 256, 0, stream>>>(deg, bsum);
  scan_block<<<1, 256, 0, stream>>>(bsum, SCB);
  scan_final<<<SCB, 256, 0, stream>>>(deg, bsum, off);
  hipMemcpyAsync(cur, off, (size_t)NBINS*4, hipMemcpyDeviceToDevice, stream);
  scatter_sort<<<(NE+255)/256, 256, 0, stream>>>(esrc, edst, etyp, cur, srcS);
  build_bfrag_msg<<<(NT*5*10*2*512+255)/256, 256, 0, stream>>>(W_e, BfE2);
  build_bfrag_gru<<<(10*3*2*2*5*512+255)/256, 256, 0, stream>>>(w_ih, w_hh, BfG);
  init_h<<<(int)(((long long)NN*HS + 255)/256), 256, 0, stream>>>(nodes, h0);

  // ping-pong with in-place GRU: msg writes inc into the dead buffer,
  // gru overwrites it with hnext. 2 buffers total.
  float* hb[2] = {h0, h1};
  const int grows = (NN + 63)/64;        // 1563 (64 rows/block for both kernels)
  for (int pass = 0; pass < NPASS; pass++){
    const float* hc = hb[pass & 1];
    float*       hn = hb[(pass + 1) & 1];
    msg_kernel<<<grows, 256, 0, stream>>>(hc, srcS, off, deg, b_e, BfE2, hn);
    gru_kernel<<<grows, 256, 0, stream>>>(hc, hn, BfG, b_ih, b_hh);
  }

  readout1<<<NG*RPB, 256, 0, stream>>>(hb[NPASS & 1], gids, part);
  readout2<<<NG, 256, 0, stream>>>(part, pclass, xbuf);
  fc1_kernel<<<NG, HIDN, 0, stream>>>(xbuf, fc1w, fc1b, hidb);
  fc2_kernel<<<NG, 64, 0, stream>>>(hidb, fc2w, fc2b, out);
}

// Round 14
// 1814.342 us; speedup vs baseline: 1.1707x; 1.1707x over previous
//
#include <hip/hip_runtime.h>
#include <hip/hip_bf16.h>
#include <cstdint>
#include <cstddef>

#define NN 100000
#define NE 800000
#define NG 64
#define NT 4
#define DD 150
#define HS 160    // padded h/inc row stride (floats): 640 B = 10 cache lines, 16B aligned
#define HIDN 512
#define NPASS 5
#define NBINS (NN*NT)
#define RPB 16     // readout partial blocks per graph

typedef short  s8v  __attribute__((ext_vector_type(8)));   // 8 bf16 (4 VGPRs)
typedef float  f32x4 __attribute__((ext_vector_type(4)));

static __device__ __forceinline__ float sigmoidf_(float x){ return 1.f/(1.f+expf(-x)); }
static __device__ __forceinline__ short f2bf(float x){
  __hip_bfloat16 b = __float2bfloat16(x);
  return *(short*)&b;
}
static __device__ __forceinline__ float bf2f(short s){
  union { unsigned u; float f; } v; v.u = ((unsigned)(unsigned short)s) << 16; return v.f;
}
// split fp32 into hi bf16 + residual bf16 (Markidis): x ~= hi + lo
static __device__ __forceinline__ void split_bf(float x, short& hi, short& lo){
  hi = f2bf(x);
  lo = f2bf(x - bf2f(hi));
}

// stage one 20 KB B-slice (1280 x 16B chunks) direct to LDS via global_load_lds:
// no VGPR round-trip, no ds_write. LDS dest = wave-uniform base + lane*16 (HW rule);
// global src is per-lane. All threads execute (no divergence).
static __device__ __forceinline__ void stage16(const unsigned short* __restrict__ g,
                                               short* l, int tid){
  const int wave = tid >> 6, lane = tid & 63;
  #pragma unroll
  for (int k2 = 0; k2 < 5; k2++){
    const int cb = k2*256 + wave*64;                 // wave-uniform chunk base
    const unsigned short* gp = g + (size_t)(cb + lane)*8;
    short* lp = l + (size_t)cb*8;                    // wave-uniform LDS base
    __builtin_amdgcn_global_load_lds(
        (const __attribute__((address_space(1))) void*)gp,
        (__attribute__((address_space(3))) void*)lp, 16, 0, 0);
  }
}

// ---------------- setup: counting sort of edges by (dst,type) ----------------

__global__ void count_kernel(const int* __restrict__ dst, const int* __restrict__ typ,
                             unsigned* __restrict__ deg){
  int e = blockIdx.x*256 + threadIdx.x;
  if (e < NE) atomicAdd(&deg[dst[e]*NT + typ[e]], 1u);
}

__device__ unsigned block_excl_base(unsigned threadSum){
  const int tid = threadIdx.x;
  const int lane = tid & 63, wid = tid >> 6;
  unsigned s = threadSum;
  #pragma unroll
  for (int d = 1; d < 64; d <<= 1){ unsigned t = __shfl_up(s, d); if (lane >= d) s += t; }
  __shared__ unsigned wsum[4];
  if (lane == 63) wsum[wid] = s;
  __syncthreads();
  unsigned base = 0;
  for (int w = 0; w < wid; w++) base += wsum[w];
  return base + s - threadSum;
}

__global__ void scan_reduce(const unsigned* __restrict__ deg, unsigned* __restrict__ bsum){
  const int base = blockIdx.x*1024 + threadIdx.x*4;
  unsigned s = 0;
  #pragma unroll
  for (int i = 0; i < 4; i++){ const int idx = base+i; if (idx < NBINS) s += deg[idx]; }
  #pragma unroll
  for (int d = 1; d < 64; d <<= 1) s += __shfl_down(s, d);
  __shared__ unsigned ws4[4];
  const int lane = threadIdx.x & 63, wid = threadIdx.x >> 6;
  if (lane == 0) ws4[wid] = s;
  __syncthreads();
  if (threadIdx.x == 0) bsum[blockIdx.x] = ws4[0]+ws4[1]+ws4[2]+ws4[3];
}

__global__ void scan_block(unsigned* bsum, int n){
  const int tid = threadIdx.x;
  unsigned v[4]; unsigned s = 0;
  #pragma unroll
  for (int i = 0; i < 4; i++){ const int idx = tid*4+i; v[i] = (idx < n) ? bsum[idx] : 0u; s += v[i]; }
  unsigned run = block_excl_base(s);
  #pragma unroll
  for (int i = 0; i < 4; i++){ const int idx = tid*4+i; if (idx < n) bsum[idx] = run; run += v[i]; }
}

__global__ void scan_final(const unsigned* __restrict__ deg, const unsigned* __restrict__ bsum,
                           unsigned* __restrict__ off){
  const int tid = threadIdx.x;
  const int base0 = blockIdx.x*1024 + tid*4;
  unsigned v[4]; unsigned s = 0;
  #pragma unroll
  for (int i = 0; i < 4; i++){ const int idx = base0+i; v[i] = (idx < NBINS) ? deg[idx] : 0u; s += v[i]; }
  unsigned run = block_excl_base(s) + bsum[blockIdx.x];
  #pragma unroll
  for (int i = 0; i < 4; i++){ const int idx = base0+i; if (idx < NBINS) off[idx] = run; run += v[i]; }
  if (blockIdx.x == 0 && tid == 0) off[NBINS] = NE;
}

__global__ void scatter_sort(const int* __restrict__ src, const int* __restrict__ dst,
                             const int* __restrict__ typ, unsigned* __restrict__ cur,
                             int* __restrict__ srcSorted){
  int e = blockIdx.x*256 + threadIdx.x;
  if (e < NE){
    const int bin = dst[e]*NT + typ[e];
    const unsigned p = atomicAdd(&cur[bin], 1u);
    srcSorted[p] = src[e];
  }
}

// ---------------- h init: copy nodes into padded-stride buffer, zero pads ----------
__global__ void init_h(const float* __restrict__ nodes, float* __restrict__ h0){
  const long long idx = (long long)blockIdx.x*256 + threadIdx.x;
  if (idx >= (long long)NN*HS) return;
  const int row = (int)(idx / HS), col = (int)(idx % HS);
  float v = 0.f;
  if (col < DD) v = nodes[(size_t)row*DD + col];
  h0[idx] = v;
}

// ---- pack W_e -> slice-ordered msg B-frags: BfE2[(t*5+s)][i*2+c][512], c:0=hi 1=lo
__global__ void build_bfrag_msg(const float* __restrict__ W, unsigned short* __restrict__ out){
  const int idx = blockIdx.x*256 + threadIdx.x;
  if (idx >= NT*5*10*2*512) return;
  const int w = idx & 511;
  int r = idx >> 9;
  const int c = r % 2;  r /= 2;
  const int i = r % 10; r /= 10;
  const int s = r % 5;  const int t = r / 5;
  const int l = w >> 3, j = w & 7;
  const int n  = 16*i + (l & 15);
  const int kk = 32*s + (l >> 4)*8 + j;
  float v = 0.f;
  if (n < DD && kk < DD) v = W[(size_t)(t*DD + n)*DD + kk];
  short hi, lo; split_bf(v, hi, lo);
  out[(size_t)((t*5 + s)*20 + i*2 + c)*512 + w] = (unsigned short)(c ? lo : hi);
}

// ---- pack w_ih/w_hh -> slice-ordered gru B-frags (20 KB slices, 2 products each):
// BfG[(iT*3+part)][u*10 + c*5 + s][512]; product P=part*2+u: g=P>>1, src=P&1 (0=I,1=H)
__global__ void build_bfrag_gru(const float* __restrict__ w_ih, const float* __restrict__ w_hh,
                                unsigned short* __restrict__ out){
  const int idx = blockIdx.x*256 + threadIdx.x;
  if (idx >= 10*3*2*2*5*512) return;
  const int w = idx & 511;
  int r = idx >> 9;
  const int s = r % 5;    r /= 5;
  const int c = r % 2;    r /= 2;
  const int u = r % 2;    r /= 2;
  const int part = r % 3; const int iT = r / 3;
  const int P = part*2 + u;
  const int g = P >> 1;
  const float* W = (P & 1) ? w_hh : w_ih;
  const int l = w >> 3, j = w & 7;
  const int n  = 16*iT + (l & 15);
  const int kk = 32*s + (l >> 4)*8 + j;
  float v = 0.f;
  if (n < DD && kk < DD) v = W[(size_t)(g*DD + n)*DD + kk];
  short hi, lo; split_bf(v, hi, lo);
  out[(size_t)((iT*3 + part)*20 + u*10 + c*5 + s)*512 + w] = (unsigned short)(c ? lo : hi);
}

// 3-product split-precision accumulate: acc += (Ahi+Alo)*(Bhi+Blo) minus lo*lo
#define MFMA3(acc, ahi, alo, bhi, blo) \
  acc = __builtin_amdgcn_mfma_f32_16x16x32_bf16(ahi, bhi, acc, 0,0,0); \
  acc = __builtin_amdgcn_mfma_f32_16x16x32_bf16(alo, bhi, acc, 0,0,0); \
  acc = __builtin_amdgcn_mfma_f32_16x16x32_bf16(ahi, blo, acc, 0,0,0);

// ---------------- kernel A: gather + message GEMM -> inc (global) -------------
// 256 thr / 4 waves / 64 rows; LDS 2x20 KB -> 4 blocks/CU (4 x 40960 = 160 KiB).
// B-slices staged direct-to-LDS via global_load_lds (width 16). One barrier per
// slice except the dead last one. CSR offsets via one uint4 + scalar.
__global__ __launch_bounds__(256, 2) void msg_kernel(
    const float* __restrict__ h, const int* __restrict__ srcS,
    const unsigned* __restrict__ off, const unsigned* __restrict__ deg,
    const float* __restrict__ b_e,
    const unsigned short* __restrict__ BfE2,
    float* __restrict__ inc)
{
  __shared__ short Bs[2][20*512];   // 2 x 20480 B
  const int tid = threadIdx.x, wave = tid >> 6, l = tid & 63;
  const int m = l & 15, q = l >> 4, q8 = q*8;
  const int arow = blockIdx.x*64 + wave*16 + m;
  const bool av = (arow < NN);
  const int lb8 = l*8;

  f32x4 acc[10];
  #pragma unroll
  for (int i = 0; i < 10; i++) acc[i] = (f32x4)(0.0f);

  // all 5 CSR offsets for this row in one uint4 + scalar
  unsigned ob0=0, ob1=0, ob2=0, ob3=0, ob4=0;
  if (av){
    const uint4 ob = *(const uint4*)&off[arow*NT];
    ob0=ob.x; ob1=ob.y; ob2=ob.z; ob3=ob.w;
    ob4 = off[arow*NT + 4];
  }

  // prologue: slices 0 and 1 direct to LDS (land during first gather)
  stage16(BfE2,          &Bs[0][0], tid);
  stage16(BfE2 + 10240,  &Bs[1][0], tid);
  __syncthreads();

  for (int t = 0; t < NT; t++){
    // pre-gather: stage slice t*5+1 for t>0 (t=0's slice 1 staged in prologue).
    if (t > 0) stage16(BfE2 + (size_t)(t*5 + 1)*10240, &Bs[(t*5+1) & 1][0], tid);

    // ---- gather type-t neighbor rows ----
    float a[5][8];
    #pragma unroll
    for (int s = 0; s < 5; s++)
      #pragma unroll
      for (int j = 0; j < 8; j++) a[s][j] = 0.f;

    const int lo = (int)((t==0)?ob0:(t==1)?ob1:(t==2)?ob2:ob3);
    const int hi = (int)((t==0)?ob1:(t==1)?ob2:(t==2)?ob3:ob4);
    int e = lo;
    int i0 = (e   < hi) ? srcS[e]   : 0;
    int i1 = (e+1 < hi) ? srcS[e+1] : -1;
    while (e < hi){
      const int n0 = (e+2 < hi) ? srcS[e+2] : 0;
      const int n1 = (e+3 < hi) ? srcS[e+3] : -1;
      const float* p0 = h + (size_t)i0*HS + q8;
      const float* p1 = h + (size_t)(i1 < 0 ? 0 : i1)*HS + q8;
      const float w1 = (i1 < 0) ? 0.f : 1.f;
      f32x4 v[10], u[10];
      #pragma unroll
      for (int s = 0; s < 5; s++){
        v[2*s]   = *(const f32x4*)(p0 + 32*s);
        v[2*s+1] = *(const f32x4*)(p0 + 32*s + 4);
      }
      #pragma unroll
      for (int s = 0; s < 5; s++){
        u[2*s]   = *(const f32x4*)(p1 + 32*s);
        u[2*s+1] = *(const f32x4*)(p1 + 32*s + 4);
      }
      #pragma unroll
      for (int s = 0; s < 5; s++){
        #pragma unroll
        for (int j = 0; j < 4; j++){
          a[s][j]   += v[2*s][j];
          a[s][j]   = fmaf(w1, u[2*s][j], a[s][j]);
          a[s][4+j] += v[2*s+1][j];
          a[s][4+j] = fmaf(w1, u[2*s+1][j], a[s][4+j]);
        }
      }
      e += 2; i0 = n0; i1 = n1;
    }

    s8v af_hi[5], af_lo[5];
    #pragma unroll
    for (int s = 0; s < 5; s++)
      #pragma unroll
      for (int j = 0; j < 8; j++){
        short h2, l2; split_bf(a[s][j], h2, l2);
        af_hi[s][j] = h2; af_lo[s][j] = l2;
      }

    // ---- 5 staged MFMA slices for this t; stage slice sidx+1 at slice top ----
    #pragma unroll
    for (int st = 0; st < 5; st++){
      const int sidx = t*5 + st;
      if (st >= 1 && sidx + 1 < 20)
        stage16(BfE2 + (size_t)(sidx+1)*10240, &Bs[(sidx+1) & 1][0], tid);
      const short* bsr = &Bs[sidx & 1][0];
      #pragma unroll
      for (int i = 0; i < 10; i++){
        const s8v bh = *(const s8v*)(bsr + (i*2+0)*512 + lb8);
        const s8v bl = *(const s8v*)(bsr + (i*2+1)*512 + lb8);
        MFMA3(acc[i], af_hi[st], af_lo[st], bh, bl)
      }
      if (sidx < 19) __syncthreads();   // drains staged loads + frees buf[sidx&1]
    }
  }

  // store inc (+ deg@b_e bias) in C-layout; cols >= DD zeroed (MFMA K pad later)
  const int crow0 = blockIdx.x*64 + wave*16 + q*4;
  #pragma unroll
  for (int r = 0; r < 4; r++){
    const int crow = crow0 + r;
    if (crow < NN){
      const uint4 dg = *(const uint4*)(&deg[crow*NT]);
      const float d0=(float)dg.x, d1=(float)dg.y, d2=(float)dg.z, d3=(float)dg.w;
      float* op = inc + (size_t)crow*HS;
      #pragma unroll
      for (int i = 0; i < 10; i++){
        const int c = 16*i + m;
        float val = 0.f;
        if (c < DD)
          val = acc[i][r] + fmaf(d0, b_e[c], fmaf(d1, b_e[DD+c],
                  fmaf(d2, b_e[2*DD+c], d3*b_e[3*DD+c])));
        op[c] = val;
      }
    }
  }
}

// ---------------- kernel B: gi/gh GEMMs + GRU, IN PLACE over inc --------------
// 256 thr / 4 waves / 64 rows; 30 x 20 KB slices double-buffered via
// global_load_lds. Independent tI/tH MFMA chains (2x ILP).
// ONE-ITERATION deferred stores: part-2 results go to hnT[4] (5 regs, static),
// the barrier is crossed, and the 4 stores issue at the TOP of the next
// iteration -- they retire under a full slice of stage+MFMA before the next
// vmcnt(0) drain. (Round-12/13 lesson: whole-kernel deferral in hn[10][4]
// spills to scratch; this keeps the barrier-path relief at 5 registers.)
// In-place safe: block reads only its own 64 inc rows, overwrites same rows.
__global__ __launch_bounds__(256, 2) void gru_kernel(
    const float* __restrict__ h, float* __restrict__ incnext,
    const unsigned short* __restrict__ BfG,
    const float* __restrict__ b_ih, const float* __restrict__ b_hh)
{
  __shared__ short Bs[2][20*512];   // 2 x 20480 B
  const int tid = threadIdx.x, wave = tid >> 6, l = tid & 63;
  const int m = l & 15, q = l >> 4, q8 = q*8;
  const int arow = blockIdx.x*64 + wave*16 + m;
  const bool av = (arow < NN);
  const int lb8 = l*8;
  const int crow0 = blockIdx.x*64 + wave*16 + q*4;

  // stage slice 0 first so it lands under the A-fragment build
  stage16(BfG, &Bs[0][0], tid);

  // A-fragments: inc and hcur from global padded rows (uniform aligned loads)
  s8v afi_h[5], afi_l[5], afh_h[5], afh_l[5];
  {
    const float* ip = incnext + (size_t)(av ? arow : 0)*HS;
    const float* hp = h       + (size_t)(av ? arow : 0)*HS;
    #pragma unroll
    for (int s = 0; s < 5; s++){
      const int b = 32*s + q8;
      const f32x4 x0 = *(const f32x4*)(ip + b), x1 = *(const f32x4*)(ip + b + 4);
      const f32x4 y0 = *(const f32x4*)(hp + b), y1 = *(const f32x4*)(hp + b + 4);
      #pragma unroll
      for (int j = 0; j < 4; j++){
        short h2, l2;
        split_bf(x0[j], h2, l2); afi_h[s][j]   = h2; afi_l[s][j]   = l2;
        split_bf(x1[j], h2, l2); afi_h[s][4+j] = h2; afi_l[s][4+j] = l2;
        split_bf(y0[j], h2, l2); afh_h[s][j]   = h2; afh_l[s][j]   = l2;
        split_bf(y1[j], h2, l2); afh_h[s][4+j] = h2; afh_l[s][4+j] = l2;
      }
    }
  }
  __syncthreads();   // slice 0 landed

  f32x4 aR=(f32x4)(0.f), aZ=(f32x4)(0.f);
  float hv[4] = {0.f,0.f,0.f,0.f};
  float hnT[4];      // one iT's deferred outputs (static indices only)
  int   pcol = -1;   // pending store column (per-lane; -1 = none)

  for (int k = 0; k < 30; k++){
    // flush the previous part-2's stores right after its barrier: they drain
    // during this slice's stage+MFMA work instead of on the barrier path
    if (pcol >= 0){
      #pragma unroll
      for (int r = 0; r < 4; r++){
        const int crow = crow0 + r;
        if (crow < NN) incnext[(size_t)crow*HS + pcol] = hnT[r];
      }
      pcol = -1;
    }

    // stage slice k+1 direct to LDS
    if (k + 1 < 30) stage16(BfG + (size_t)(k+1)*10240, &Bs[(k+1) & 1][0], tid);

    const int iT = k/3, part = k - 3*iT;
    const int d = 16*iT + m;
    if (part == 0){
      #pragma unroll
      for (int r = 0; r < 4; r++){
        hv[r] = 0.f;
        if (crow0 + r < NN && d < DD) hv[r] = h[(size_t)(crow0+r)*HS + d];
      }
    }

    // slice k holds products u=0 (pairs with afi) and u=1 (pairs with afh);
    // accumulate them in independent chains tI / tH (2x MFMA ILP)
    const short* bsr = &Bs[k & 1][0];
    f32x4 tI = (f32x4)(0.f), tH = (f32x4)(0.f);
    #pragma unroll
    for (int s = 0; s < 5; s++){
      const s8v b0h = *(const s8v*)(bsr + (     s)*512 + lb8);
      const s8v b0l = *(const s8v*)(bsr + ( 5 + s)*512 + lb8);
      const s8v b1h = *(const s8v*)(bsr + (10 + s)*512 + lb8);
      const s8v b1l = *(const s8v*)(bsr + (15 + s)*512 + lb8);
      MFMA3(tI, afi_h[s], afi_l[s], b0h, b0l)
      MFMA3(tH, afh_h[s], afh_l[s], b1h, b1l)
    }

    if (part == 0){
      aR = tI + tH;
    } else if (part == 1){
      aZ = tI + tH;
    } else if (d < DD){   // part 2: tI = N_i product, tH = N_h product
      const float br   = b_ih[d]    + b_hh[d];
      const float bz   = b_ih[DD+d] + b_hh[DD+d];
      const float bin2 = b_ih[2*DD+d];
      const float bhn  = b_hh[2*DD+d];
      #pragma unroll
      for (int r = 0; r < 4; r++){
        const float rr = sigmoidf_(aR[r] + br);
        const float zz = sigmoidf_(aZ[r] + bz);
        const float nn = tanhf(tI[r] + bin2 + rr*(tH[r] + bhn));
        hnT[r] = (1.f - zz)*nn + zz*hv[r];
      }
      pcol = d;          // defer the 4 stores past the barrier
    }
    if (k < 29) __syncthreads();   // drains staged loads + frees buf[k&1]
  }

  // final flush (iT = 9)
  if (pcol >= 0){
    #pragma unroll
    for (int r = 0; r < 4; r++){
      const int crow = crow0 + r;
      if (crow < NN) incnext[(size_t)crow*HS + pcol] = hnT[r];
    }
  }
}

// ---------------- readout: two-stage segment sum, log/nan/relu, concat ----------------
__global__ void readout1(const float* __restrict__ h, const int* __restrict__ gids,
                         float* __restrict__ part){
  const int g = blockIdx.x >> 4, s = blockIdx.x & (RPB-1);
  const int tid = threadIdx.x;
  __shared__ int sb[2];
  if (tid < 2){
    const int target = g + tid;
    int lo = 0, hi = NN;
    while (lo < hi){ const int mid = (lo+hi) >> 1; if (gids[mid] < target) lo = mid+1; else hi = mid; }
    sb[tid] = lo;
  }
  __syncthreads();
  const int lo = sb[0], hi = sb[1];
  const int len = hi - lo;
  const int per = (len + RPB - 1) / RPB;
  const int nlo = lo + s*per;
  const int nhi = (nlo + per < hi) ? (nlo + per) : hi;
  if (tid < DD){
    float acc = 0.f;
    for (int n = nlo; n < nhi; n++) acc += h[(size_t)n*HS + tid];
    part[(size_t)blockIdx.x*DD + tid] = acc;
  }
}

__global__ void readout2(const float* __restrict__ part, const float* __restrict__ pclass,
                         float* __restrict__ xbuf){
  const int g = blockIdx.x, tid = threadIdx.x;
  if (tid < DD){
    float acc = 0.f;
    #pragma unroll
    for (int s = 0; s < RPB; s++) acc += part[(size_t)(g*RPB + s)*DD + tid];
    float l = logf(acc);            // log(neg)=NaN, log(0)=-inf
    if (isnan(l)) l = 0.f;          // nan -> 0
    l = fmaxf(l, 0.f);              // relu (also kills -inf)
    xbuf[g*(DD+1)+tid] = l;
  }
  if (tid == DD) xbuf[g*(DD+1)+DD] = pclass[g];
}

__global__ void fc1_kernel(const float* __restrict__ xbuf, const float* __restrict__ w,
                           const float* __restrict__ b, float* __restrict__ hid){
  const int g = blockIdx.x, tid = threadIdx.x;   // 512 threads
  __shared__ float xs[DD+1];
  if (tid < DD+1) xs[tid] = xbuf[g*(DD+1)+tid];
  __syncthreads();
  float acc = b[tid];
  for (int k = 0; k < DD+1; k++) acc = fmaf(xs[k], w[k*HIDN + tid], acc);
  hid[g*HIDN + tid] = (acc > 0.f) ? acc : 0.01f*acc;   // leaky_relu(0.01)
}

__global__ void fc2_kernel(const float* __restrict__ hid, const float* __restrict__ w,
                           const float* __restrict__ b, float* __restrict__ out){
  const int g = blockIdx.x, tid = threadIdx.x;   // 64 threads
  __shared__ float hs[HIDN];
  for (int i = tid; i < HIDN; i += 64) hs[i] = hid[g*HIDN + i];
  __syncthreads();
  if (tid < 10){
    float acc = b[tid];
    for (int k = 0; k < HIDN; k++) acc = fmaf(hs[k], w[k*10 + tid], acc);
    out[g*10 + tid] = acc;
  }
}

// ---------------- host orchestration ----------------
extern "C" void kernel_launch(void* const* d_in, const int* in_sizes, int n_in,
                              void* d_out, int out_size, void* d_ws, size_t ws_size,
                              hipStream_t stream)
{
  (void)in_sizes; (void)n_in; (void)out_size; (void)ws_size;
  const float* nodes  = (const float*)d_in[0];
  const float* pclass = (const float*)d_in[1];
  const int*   esrc   = (const int*)d_in[2];
  const int*   edst   = (const int*)d_in[3];
  const int*   etyp   = (const int*)d_in[4];
  const int*   gids   = (const int*)d_in[5];
  const float* W_e    = (const float*)d_in[6];
  const float* b_e    = (const float*)d_in[7];
  const float* w_ih   = (const float*)d_in[8];
  const float* w_hh   = (const float*)d_in[9];
  const float* b_ih   = (const float*)d_in[10];
  const float* b_hh   = (const float*)d_in[11];
  const float* fc1w   = (const float*)d_in[12];
  const float* fc1b   = (const float*)d_in[13];
  const float* fc2w   = (const float*)d_in[14];
  const float* fc2b   = (const float*)d_in[15];
  float* out = (float*)d_out;

  char* p = (char*)d_ws;
  auto alloc = [&](size_t bytes)->char* {
    char* r = p; p += ((bytes + 255) & ~(size_t)255); return r;
  };
  float*    h0   = (float*)alloc((size_t)NN*HS*4);          // 64 MB (ping)
  float*    h1   = (float*)alloc((size_t)NN*HS*4);          // 64 MB (pong; also inc)
  unsigned* deg  = (unsigned*)alloc((size_t)NBINS*4);
  unsigned* off  = (unsigned*)alloc((size_t)(NBINS+1)*4);
  unsigned* cur  = (unsigned*)alloc((size_t)NBINS*4);
  unsigned* bsum = (unsigned*)alloc(4096);
  int*      srcS = (int*)alloc((size_t)NE*4);
  unsigned short* BfE2 = (unsigned short*)alloc((size_t)20*20*512*2);   // 409,600 B
  unsigned short* BfG  = (unsigned short*)alloc((size_t)30*20*512*2);   // 614,400 B
  float*    part = (float*)alloc((size_t)NG*RPB*DD*4);
  float*    xbuf = (float*)alloc((size_t)NG*(DD+1)*4);
  float*    hidb = (float*)alloc((size_t)NG*HIDN*4);

  // --- per-launch setup: edge CSR sort + slice-packed weights + h init ---
  hipMemsetAsync(deg, 0, (size_t)NBINS*4, stream);
  count_kernel<<<(NE+255)/256, 256, 0, stream>>>(edst, etyp, deg);
  const int SCB = (NBINS + 1023)/1024;   // 391
  scan_reduce<<<SCB, 256, 0, stream>>>(deg, bsum);
  scan_block<<<1, 256, 0, stream>>>(bsum, SCB);
  scan_final<<<SCB, 256, 0, stream>>>(deg, bsum, off);
  hipMemcpyAsync(cur, off, (size_t)NBINS*4, hipMemcpyDeviceToDevice, stream);
  scatter_sort<<<(NE+255)/256, 256, 0, stream>>>(esrc, edst, etyp, cur, srcS);
  build_bfrag_msg<<<(NT*5*10*2*512+255)/256, 256, 0, stream>>>(W_e, BfE2);
  build_bfrag_gru<<<(10*3*2*2*5*512+255)/256, 256, 0, stream>>>(w_ih, w_hh, BfG);
  init_h<<<(int)(((long long)NN*HS + 255)/256), 256, 0, stream>>>(nodes, h0);

  // ping-pong with in-place GRU: msg writes inc into the dead buffer,
  // gru overwrites it with hnext. 2 buffers total.
  float* hb[2] = {h0, h1};
  const int grows = (NN + 63)/64;        // 1563 (64 rows/block for both kernels)
  for (int pass = 0; pass < NPASS; pass++){
    const float* hc = hb[pass & 1];
    float*       hn = hb[(pass + 1) & 1];
    msg_kernel<<<grows, 256, 0, stream>>>(hc, srcS, off, deg, b_e, BfE2, hn);
    gru_kernel<<<grows, 256, 0, stream>>>(hc, hn, BfG, b_ih, b_hh);
  }

  readout1<<<NG*RPB, 256, 0, stream>>>(hb[NPASS & 1], gids, part);
  readout2<<<NG, 256, 0, stream>>>(part, pclass, xbuf);
  fc1_kernel<<<NG, HIDN, 0, stream>>>(xbuf, fc1w, fc1b, hidb);
  fc2_kernel<<<NG, 64, 0, stream>>>(hidb, fc2w, fc2b, out);
}